// Round 6
// baseline (4552.481 us; speedup 1.0000x reference)
//
#include <hip/hip_runtime.h>
#include <hip/hip_bf16.h>
#include <cstdint>

typedef __hip_bfloat16 bf16;

// =============== naive QKV projection ===============
// C = x[4096,1024] @ W[1024,1024] (W per n-range), scatter to Q/K/V [b,h,t,64] bf16
// grid (96,128), block (16,16); 32x32 tile, 2x2 per thread, f32 compute.
__global__ __launch_bounds__(256) void qkv_naive(
    const float* __restrict__ A,
    const float* __restrict__ Wq, const float* __restrict__ Wk, const float* __restrict__ Wv,
    bf16* __restrict__ Qb, bf16* __restrict__ Kb, bf16* __restrict__ Vb) {
  __shared__ float As[32][17];
  __shared__ float Ws[16][33];
  const int tx = threadIdx.x, ty = threadIdx.y;
  const int tid = ty * 16 + tx;
  const int n0 = blockIdx.x * 32;   // 0..3071
  const int m0 = blockIdx.y * 32;   // 0..4095
  const float* W = (n0 < 1024) ? Wq : ((n0 < 2048) ? Wk : Wv);
  const int nl0 = n0 & 1023;

  float c00 = 0.f, c01 = 0.f, c10 = 0.f, c11 = 0.f;
  const int ar = tid >> 3, ac = (tid & 7) * 2;    // A: 32 rows x 16 cols
  const int wr = tid >> 4, wc = (tid & 15) * 2;   // W: 16 rows x 32 cols

  for (int k0 = 0; k0 < 1024; k0 += 16) {
    As[ar][ac]     = A[(long)(m0 + ar) * 1024 + k0 + ac];
    As[ar][ac + 1] = A[(long)(m0 + ar) * 1024 + k0 + ac + 1];
    Ws[wr][wc]     = W[(long)(k0 + wr) * 1024 + nl0 + wc];
    Ws[wr][wc + 1] = W[(long)(k0 + wr) * 1024 + nl0 + wc + 1];
    __syncthreads();
#pragma unroll
    for (int k = 0; k < 16; ++k) {
      const float a0 = As[ty][k], a1 = As[ty + 16][k];
      const float b0 = Ws[k][tx], b1 = Ws[k][tx + 16];
      c00 += a0 * b0; c01 += a0 * b1; c10 += a1 * b0; c11 += a1 * b1;
    }
    __syncthreads();
  }

  // scatter: row gm = b*2048+t ; col n -> (which, h, hd)
  const float cv[2][2] = {{c00, c01}, {c10, c11}};
#pragma unroll
  for (int im = 0; im < 2; ++im) {
#pragma unroll
    for (int in = 0; in < 2; ++in) {
      const int gm = m0 + ty + im * 16;
      const int n = n0 + tx + in * 16;
      const int which = n >> 10, rem = n & 1023;
      const int h = rem >> 6, hd = rem & 63;
      const int b = gm >> 11, t = gm & 2047;
      bf16* dst = (which == 0) ? Qb : ((which == 1) ? Kb : Vb);
      dst[(((long)(b * 16 + h)) * 2048 + t) * 64 + hd] = __float2bfloat16(cv[im][in]);
    }
  }
}

// =============== naive causal attention ===============
// grid (32, 32) = (q-tile, b*16+h), block 256. Two-pass (max, then sum+PV).
// Q/K/V [b,h,t,64] bf16; all arithmetic f32; LDS-staged 64-tiles.
__global__ __launch_bounds__(256) void attn_naive(
    const bf16* __restrict__ Q, const bf16* __restrict__ Kg, const bf16* __restrict__ Vg,
    bf16* __restrict__ ctx) {
  __shared__ float Qs[64][65];
  __shared__ float Ks[64][65];
  __shared__ float Vs[64][65];
  __shared__ float Ps[64][65];
  __shared__ float red[64][4];
  __shared__ float Mq[64];
  __shared__ float Lq[64];

  const int tid = threadIdx.x;
  const int q = tid >> 2;        // 0..63 local query row
  const int g = tid & 3;         // 0..3  16-col group
  const int qt = blockIdx.x;
  const int bh = blockIdx.y;
  const int q0 = qt * 64;
  const long base = (long)bh * 2048 * 64;
  const int qglob = q0 + q;

  for (int i = 0; i < 16; ++i)
    Qs[q][g * 16 + i] = __bfloat162float(Q[base + (long)qglob * 64 + g * 16 + i]);
  __syncthreads();

  // ---- pass 1: row max of scaled, masked scores ----
  float m = -1e30f;
  for (int kt = 0; kt <= qt; ++kt) {
    for (int i = 0; i < 16; ++i)
      Ks[q][g * 16 + i] = __bfloat162float(Kg[base + (long)(kt * 64 + q) * 64 + g * 16 + i]);
    __syncthreads();
    for (int i = 0; i < 16; ++i) {
      const int k = g * 16 + i;
      const int kidx = kt * 64 + k;
      if (kidx <= qglob) {
        float s = 0.f;
        for (int d = 0; d < 64; ++d) s += Qs[q][d] * Ks[k][d];
        m = fmaxf(m, s * 0.125f);
      }
    }
    __syncthreads();
  }
  red[q][g] = m;
  __syncthreads();
  if (g == 0)
    Mq[q] = fmaxf(fmaxf(red[q][0], red[q][1]), fmaxf(red[q][2], red[q][3]));
  __syncthreads();
  m = Mq[q];

  // ---- pass 2: P = exp(s - m), denominator, and P@V ----
  float l = 0.f;
  float acc[16];
#pragma unroll
  for (int i = 0; i < 16; ++i) acc[i] = 0.f;

  for (int kt = 0; kt <= qt; ++kt) {
    for (int i = 0; i < 16; ++i) {
      Ks[q][g * 16 + i] = __bfloat162float(Kg[base + (long)(kt * 64 + q) * 64 + g * 16 + i]);
      Vs[q][g * 16 + i] = __bfloat162float(Vg[base + (long)(kt * 64 + q) * 64 + g * 16 + i]);
    }
    __syncthreads();
    for (int i = 0; i < 16; ++i) {
      const int k = g * 16 + i;
      const int kidx = kt * 64 + k;
      float p = 0.f;
      if (kidx <= qglob) {
        float s = 0.f;
        for (int d = 0; d < 64; ++d) s += Qs[q][d] * Ks[k][d];
        p = expf(s * 0.125f - m);
        l += p;
      }
      Ps[q][k] = p;
    }
    __syncthreads();
    for (int k = 0; k < 64; ++k) {
      const float p = Ps[q][k];
#pragma unroll
      for (int i = 0; i < 16; ++i) acc[i] += p * Vs[k][g * 16 + i];
    }
    __syncthreads();
  }

  red[q][g] = l;
  __syncthreads();
  if (g == 0) Lq[q] = red[q][0] + red[q][1] + red[q][2] + red[q][3];
  __syncthreads();
  const float inv = 1.f / Lq[q];

  const int b = bh >> 4, h = bh & 15;
  for (int i = 0; i < 16; ++i)
    ctx[((long)b * 2048 + qglob) * 1024 + h * 64 + g * 16 + i] =
        __float2bfloat16(acc[i] * inv);
}

// =============== naive output projection (f32 OUTPUT) ===============
// out = ctx[4096,1024](bf16) @ wo[1024,1024](f32) + bo ; grid (32,128), block (16,16)
__global__ __launch_bounds__(256) void out_naive(
    const bf16* __restrict__ A, const float* __restrict__ W,
    const float* __restrict__ bias, float* __restrict__ out) {
  __shared__ float As[32][17];
  __shared__ float Ws[16][33];
  const int tx = threadIdx.x, ty = threadIdx.y;
  const int tid = ty * 16 + tx;
  const int n0 = blockIdx.x * 32;
  const int m0 = blockIdx.y * 32;

  float c00 = 0.f, c01 = 0.f, c10 = 0.f, c11 = 0.f;
  const int ar = tid >> 3, ac = (tid & 7) * 2;
  const int wr = tid >> 4, wc = (tid & 15) * 2;

  for (int k0 = 0; k0 < 1024; k0 += 16) {
    As[ar][ac]     = __bfloat162float(A[(long)(m0 + ar) * 1024 + k0 + ac]);
    As[ar][ac + 1] = __bfloat162float(A[(long)(m0 + ar) * 1024 + k0 + ac + 1]);
    Ws[wr][wc]     = W[(long)(k0 + wr) * 1024 + n0 + wc];
    Ws[wr][wc + 1] = W[(long)(k0 + wr) * 1024 + n0 + wc + 1];
    __syncthreads();
#pragma unroll
    for (int k = 0; k < 16; ++k) {
      const float a0 = As[ty][k], a1 = As[ty + 16][k];
      const float b0 = Ws[k][tx], b1 = Ws[k][tx + 16];
      c00 += a0 * b0; c01 += a0 * b1; c10 += a1 * b0; c11 += a1 * b1;
    }
    __syncthreads();
  }

  const int mrow = m0 + ty, n = n0 + tx;
  out[(long)mrow * 1024 + n]             = c00 + bias[n];
  out[(long)mrow * 1024 + n + 16]        = c01 + bias[n + 16];
  out[(long)(mrow + 16) * 1024 + n]      = c10 + bias[n];
  out[(long)(mrow + 16) * 1024 + n + 16] = c11 + bias[n + 16];
}

extern "C" void kernel_launch(void* const* d_in, const int* in_sizes, int n_in,
                              void* d_out, int out_size, void* d_ws, size_t ws_size,
                              hipStream_t stream) {
  const float* x  = (const float*)d_in[0];
  const float* wq = (const float*)d_in[1];
  const float* wk = (const float*)d_in[2];
  const float* wv = (const float*)d_in[3];
  const float* wo = (const float*)d_in[4];
  const float* bo = (const float*)d_in[5];
  float* out = (float*)d_out;

  // workspace (proven-safe 32 MB envelope): Q,K,V [b,h,t,64] + ctx [b,t,D], bf16
  bf16* Qb = (bf16*)d_ws;
  bf16* Kb = Qb + 4194304;
  bf16* Vb = Kb + 4194304;
  bf16* Cx = Vb + 4194304;

  hipLaunchKernelGGL(qkv_naive, dim3(96, 128), dim3(16, 16), 0, stream,
                     x, wq, wk, wv, Qb, Kb, Vb);

  hipLaunchKernelGGL(attn_naive, dim3(32, 32), dim3(256), 0, stream, Qb, Kb, Vb, Cx);

  hipLaunchKernelGGL(out_naive, dim3(32, 128), dim3(16, 16), 0, stream,
                     Cx, wo, bo, out);
}

// Round 7
// 358.694 us; speedup vs baseline: 12.6918x; 12.6918x over previous
//
#include <hip/hip_runtime.h>
#include <hip/hip_bf16.h>
#include <cstdint>

typedef __hip_bfloat16 bf16;
typedef __bf16 bf16x8 __attribute__((ext_vector_type(8)));
typedef __bf16 bf16x4 __attribute__((ext_vector_type(4)));
typedef float f32x4 __attribute__((ext_vector_type(4)));

#define LOG2E 1.4426950408889634f

// ---- QKV GEMM: C = x[M,K](f32) * W[K,1024](f32->bf16), 128x128 tile, BK=32 ----
// W picked from {Wq,Wk,Wv} by n0; epilogue scatters to Q,K,V [b,h,t,64] bf16.
__global__ __launch_bounds__(256, 2) void gemm_qkv(
    const float* __restrict__ A,
    const float* __restrict__ Wq, const float* __restrict__ Wk, const float* __restrict__ Wv,
    bf16* __restrict__ Cq, bf16* __restrict__ Ck, bf16* __restrict__ Cv,
    int M, int K) {
  constexpr int BM = 128, BN = 128, BK = 32, BSTR = 40;
  __shared__ __align__(16) bf16 As[BM * BK];
  __shared__ __align__(16) bf16 Bs[BN * BSTR];

  const int tid = threadIdx.x;
  const int lane = tid & 63;
  const int wave = tid >> 6;
  const int quad = lane >> 4;
  const int l16 = lane & 15;
  const int m0 = blockIdx.y * BM;
  const int n0 = blockIdx.x * BN;
  const int wm = (wave >> 1) * 64;
  const int wn = (wave & 1) * 64;

  const float* W = (n0 < 1024) ? Wq : ((n0 < 2048) ? Wk : Wv);
  const int nloc = n0 & 1023;

  const f32x4 zero4 = {0.f, 0.f, 0.f, 0.f};
  f32x4 acc[4][4];
#pragma unroll
  for (int mi = 0; mi < 4; ++mi)
#pragma unroll
    for (int ni = 0; ni < 4; ++ni) acc[mi][ni] = zero4;

  // A staging: thread -> (row, 16-elem chunk), f32->bf16
  const int arow = tid >> 1;
  const int ac = (tid & 1) * 16;
  const float* agp = A + (long)(m0 + arow) * K + ac;
  // B staging: thread -> (4 k-rows, 4 n-cols); Bs[n][k] = W[k0+k][nloc+n]
  const int bkq = (tid >> 5) * 4;
  const int bn4 = (tid & 31) * 4;
  const float* wgp = W + (long)bkq * 1024 + nloc + bn4;

  for (int k0 = 0; k0 < K; k0 += BK) {
    {
      const f32x4* ap = (const f32x4*)(agp + k0);
      f32x4 a0 = ap[0], a1 = ap[1], a2 = ap[2], a3 = ap[3];
      bf16x8 v0, v1;
#pragma unroll
      for (int j = 0; j < 4; ++j) { v0[j] = (__bf16)a0[j]; v0[4 + j] = (__bf16)a1[j]; }
#pragma unroll
      for (int j = 0; j < 4; ++j) { v1[j] = (__bf16)a2[j]; v1[4 + j] = (__bf16)a3[j]; }
      *(bf16x8*)&As[arow * BK + ac] = v0;
      *(bf16x8*)&As[arow * BK + ac + 8] = v1;
    }
    {
      const float* wr = wgp + (long)k0 * 1024;
      f32x4 w0 = *(const f32x4*)(wr);
      f32x4 w1 = *(const f32x4*)(wr + 1024);
      f32x4 w2 = *(const f32x4*)(wr + 2048);
      f32x4 w3 = *(const f32x4*)(wr + 3072);
#pragma unroll
      for (int j = 0; j < 4; ++j) {
        bf16x4 t;
        t[0] = (__bf16)w0[j]; t[1] = (__bf16)w1[j];
        t[2] = (__bf16)w2[j]; t[3] = (__bf16)w3[j];
        *(bf16x4*)&Bs[(bn4 + j) * BSTR + bkq] = t;
      }
    }
    __syncthreads();

    bf16x8 af[4], bfv[4];
#pragma unroll
    for (int mi = 0; mi < 4; ++mi)
      af[mi] = *(const bf16x8*)&As[(wm + mi * 16 + l16) * BK + quad * 8];
#pragma unroll
    for (int ni = 0; ni < 4; ++ni)
      bfv[ni] = *(const bf16x8*)&Bs[(wn + ni * 16 + l16) * BSTR + quad * 8];
#pragma unroll
    for (int mi = 0; mi < 4; ++mi)
#pragma unroll
      for (int ni = 0; ni < 4; ++ni)
        acc[mi][ni] = __builtin_amdgcn_mfma_f32_16x16x32_bf16(af[mi], bfv[ni], acc[mi][ni], 0, 0, 0);
    __syncthreads();
  }

  // epilogue scatter: row = b*2048+t ; col n -> (which,h,hd)
#pragma unroll
  for (int mi = 0; mi < 4; ++mi) {
    const int gmb = m0 + wm + mi * 16 + quad * 4;
#pragma unroll
    for (int ni = 0; ni < 4; ++ni) {
      const int n = n0 + wn + ni * 16 + l16;
      const int which = n >> 10, rem = n & 1023;
      const int h = rem >> 6, hd = rem & 63;
      bf16* dst = (which == 0) ? Cq : ((which == 1) ? Ck : Cv);
#pragma unroll
      for (int r = 0; r < 4; ++r) {
        const int gm = gmb + r;
        const int b = gm >> 11, t = gm & 2047;
        dst[(((long)(b * 16 + h)) * 2048 + t) * 64 + hd] = __float2bfloat16(acc[mi][ni][r]);
      }
    }
  }
}

// ---- flash attention: grid (T/64, B*H), block 256; Q,K,V in [b,h,t,64] bf16 ----
__global__ __launch_bounds__(256, 2) void attn_kernel(
    const bf16* __restrict__ Q, const bf16* __restrict__ Kg, const bf16* __restrict__ Vg,
    bf16* __restrict__ ctx) {
  constexpr int KSTR = 72;  // padded row stride
  __shared__ __align__(16) bf16 Ks[64 * KSTR];      // [t_local][d]
  __shared__ __align__(16) bf16 Vt[64 * KSTR];      // [d][t_local]
  __shared__ __align__(16) bf16 Ps[4 * 16 * KSTR];  // per-wave P [16][64]

  const int tid = threadIdx.x;
  const int lane = tid & 63;
  const int wave = tid >> 6;
  const int quad = lane >> 4;
  const int l16 = lane & 15;
  const int qt = blockIdx.x;
  const int bh = blockIdx.y;
  const int q0 = qt * 64;
  const long base = (long)bh * 2048 * 64;
  const int qrow = q0 + wave * 16;

  const bf16x8 qf0 = *(const bf16x8*)(Q + base + (long)(qrow + l16) * 64 + quad * 8);
  const bf16x8 qf1 = *(const bf16x8*)(Q + base + (long)(qrow + l16) * 64 + 32 + quad * 8);

  const f32x4 zero4 = {0.f, 0.f, 0.f, 0.f};
  float m_i[4], l_i[4];
  f32x4 oacc[4];
#pragma unroll
  for (int r = 0; r < 4; ++r) { m_i[r] = -1e30f; l_i[r] = 0.f; }
#pragma unroll
  for (int nb = 0; nb < 4; ++nb) oacc[nb] = zero4;

  const int krow = tid >> 2;        // 0..63
  const int kc = (tid & 3) * 16;    // 0,16,32,48
  const int sRow = tid >> 3;        // 0..31
  const int sCol = (tid & 7) * 8;   // 0..56

  for (int kt = 0; kt <= qt; ++kt) {
    const int k0 = kt * 64;
    {
      const bf16* kp = Kg + base + (long)(k0 + krow) * 64 + kc;
      bf16x8 a = *(const bf16x8*)kp;
      bf16x8 b = *(const bf16x8*)(kp + 8);
      *(bf16x8*)&Ks[krow * KSTR + kc] = a;
      *(bf16x8*)&Ks[krow * KSTR + kc + 8] = b;
    }
#pragma unroll
    for (int p = 0; p < 2; ++p) {
      const int row = sRow + p * 32;
      bf16x8 vv = *(const bf16x8*)(Vg + base + (long)(k0 + row) * 64 + sCol);
      const bf16* vh = (const bf16*)&vv;
#pragma unroll
      for (int i = 0; i < 8; ++i) Vt[(sCol + i) * KSTR + row] = vh[i];
    }
    __syncthreads();

    // S = Q K^T  (16 rows x 64 cols per wave)
    f32x4 s[4];
#pragma unroll
    for (int nb = 0; nb < 4; ++nb) {
      const bf16x8 kb0 = *(const bf16x8*)&Ks[(nb * 16 + l16) * KSTR + quad * 8];
      const bf16x8 kb1 = *(const bf16x8*)&Ks[(nb * 16 + l16) * KSTR + 32 + quad * 8];
      f32x4 a = zero4;
      a = __builtin_amdgcn_mfma_f32_16x16x32_bf16(qf0, kb0, a, 0, 0, 0);
      a = __builtin_amdgcn_mfma_f32_16x16x32_bf16(qf1, kb1, a, 0, 0, 0);
      s[nb] = a;
    }

    // scale + causal mask + row max
    float mp[4];
#pragma unroll
    for (int r = 0; r < 4; ++r) mp[r] = -1e30f;
#pragma unroll
    for (int nb = 0; nb < 4; ++nb) {
      const int kidx = k0 + nb * 16 + l16;
#pragma unroll
      for (int r = 0; r < 4; ++r) {
        const int qidx = qrow + quad * 4 + r;
        float sv = s[nb][r] * 0.125f;
        sv = (kidx <= qidx) ? sv : -1e30f;
        s[nb][r] = sv;
        mp[r] = fmaxf(mp[r], sv);
      }
    }
#pragma unroll
    for (int r = 0; r < 4; ++r) {
      float v = mp[r];
      v = fmaxf(v, __shfl_xor(v, 1));
      v = fmaxf(v, __shfl_xor(v, 2));
      v = fmaxf(v, __shfl_xor(v, 4));
      v = fmaxf(v, __shfl_xor(v, 8));
      mp[r] = v;
    }

    float alpha[4], mn[4], rs[4];
#pragma unroll
    for (int r = 0; r < 4; ++r) {
      mn[r] = fmaxf(m_i[r], mp[r]);
      alpha[r] = exp2f((m_i[r] - mn[r]) * LOG2E);
      rs[r] = 0.f;
    }
#pragma unroll
    for (int nb = 0; nb < 4; ++nb)
#pragma unroll
      for (int r = 0; r < 4; ++r) {
        const float p = exp2f((s[nb][r] - mn[r]) * LOG2E);
        rs[r] += p;
        Ps[wave * (16 * KSTR) + (quad * 4 + r) * KSTR + nb * 16 + l16] = __float2bfloat16(p);
      }
#pragma unroll
    for (int r = 0; r < 4; ++r) {
      float v = rs[r];
      v += __shfl_xor(v, 1);
      v += __shfl_xor(v, 2);
      v += __shfl_xor(v, 4);
      v += __shfl_xor(v, 8);
      l_i[r] = l_i[r] * alpha[r] + v;
      m_i[r] = mn[r];
    }
#pragma unroll
    for (int nb = 0; nb < 4; ++nb)
#pragma unroll
      for (int r = 0; r < 4; ++r) oacc[nb][r] *= alpha[r];

    __asm__ volatile("s_waitcnt lgkmcnt(0)" ::: "memory");

    // O += P V
    const bf16x8 pa0 = *(const bf16x8*)&Ps[wave * (16 * KSTR) + l16 * KSTR + quad * 8];
    const bf16x8 pa1 = *(const bf16x8*)&Ps[wave * (16 * KSTR) + l16 * KSTR + 32 + quad * 8];
#pragma unroll
    for (int nb2 = 0; nb2 < 4; ++nb2) {
      const bf16x8 vb0 = *(const bf16x8*)&Vt[(nb2 * 16 + l16) * KSTR + quad * 8];
      const bf16x8 vb1 = *(const bf16x8*)&Vt[(nb2 * 16 + l16) * KSTR + 32 + quad * 8];
      oacc[nb2] = __builtin_amdgcn_mfma_f32_16x16x32_bf16(pa0, vb0, oacc[nb2], 0, 0, 0);
      oacc[nb2] = __builtin_amdgcn_mfma_f32_16x16x32_bf16(pa1, vb1, oacc[nb2], 0, 0, 0);
    }
    __syncthreads();
  }

  // epilogue: ctx[b, t, h*64+hd] bf16
  const int b = bh >> 4, h = bh & 15;
#pragma unroll
  for (int r = 0; r < 4; ++r) {
    const float inv = 1.0f / l_i[r];
    const int t = qrow + quad * 4 + r;
#pragma unroll
    for (int nb2 = 0; nb2 < 4; ++nb2) {
      const int d = h * 64 + nb2 * 16 + l16;
      ctx[((long)b * 2048 + t) * 1024 + d] = __float2bfloat16(oacc[nb2][r] * inv);
    }
  }
}

// ---- output GEMM: ctx[M,K](bf16) @ wo[K,N](f32) + bo(f32) -> out f32 ----
__global__ __launch_bounds__(256, 2) void gemm_out(
    const bf16* __restrict__ A, const float* __restrict__ W,
    const float* __restrict__ bias, float* __restrict__ Cout,
    int M, int N, int K) {
  constexpr int BM = 128, BN = 128, BK = 32, BSTR = 40;
  __shared__ __align__(16) bf16 As[BM * BK];
  __shared__ __align__(16) bf16 Bs[BN * BSTR];

  const int tid = threadIdx.x;
  const int lane = tid & 63;
  const int wave = tid >> 6;
  const int quad = lane >> 4;
  const int l16 = lane & 15;
  const int m0 = blockIdx.y * BM;
  const int n0 = blockIdx.x * BN;
  const int wm = (wave >> 1) * 64;
  const int wn = (wave & 1) * 64;

  const f32x4 zero4 = {0.f, 0.f, 0.f, 0.f};
  f32x4 acc[4][4];
#pragma unroll
  for (int mi = 0; mi < 4; ++mi)
#pragma unroll
    for (int ni = 0; ni < 4; ++ni) acc[mi][ni] = zero4;

  const int arow = tid >> 1;
  const int ac = (tid & 1) * 16;
  const bf16* agp = A + (long)(m0 + arow) * K + ac;
  const int bkq = (tid >> 5) * 4;
  const int bn4 = (tid & 31) * 4;
  const float* wgp = W + (long)bkq * 1024 + n0 + bn4;

  for (int k0 = 0; k0 < K; k0 += BK) {
    {
      const bf16* ap = agp + k0;
      bf16x8 v0 = *(const bf16x8*)ap;
      bf16x8 v1 = *(const bf16x8*)(ap + 8);
      *(bf16x8*)&As[arow * BK + ac] = v0;
      *(bf16x8*)&As[arow * BK + ac + 8] = v1;
    }
    {
      const float* wr = wgp + (long)k0 * 1024;
      f32x4 w0 = *(const f32x4*)(wr);
      f32x4 w1 = *(const f32x4*)(wr + 1024);
      f32x4 w2 = *(const f32x4*)(wr + 2048);
      f32x4 w3 = *(const f32x4*)(wr + 3072);
#pragma unroll
      for (int j = 0; j < 4; ++j) {
        bf16x4 t;
        t[0] = (__bf16)w0[j]; t[1] = (__bf16)w1[j];
        t[2] = (__bf16)w2[j]; t[3] = (__bf16)w3[j];
        *(bf16x4*)&Bs[(bn4 + j) * BSTR + bkq] = t;
      }
    }
    __syncthreads();

    bf16x8 af[4], bfv[4];
#pragma unroll
    for (int mi = 0; mi < 4; ++mi)
      af[mi] = *(const bf16x8*)&As[(wm + mi * 16 + l16) * BK + quad * 8];
#pragma unroll
    for (int ni = 0; ni < 4; ++ni)
      bfv[ni] = *(const bf16x8*)&Bs[(wn + ni * 16 + l16) * BSTR + quad * 8];
#pragma unroll
    for (int mi = 0; mi < 4; ++mi)
#pragma unroll
      for (int ni = 0; ni < 4; ++ni)
        acc[mi][ni] = __builtin_amdgcn_mfma_f32_16x16x32_bf16(af[mi], bfv[ni], acc[mi][ni], 0, 0, 0);
    __syncthreads();
  }

#pragma unroll
  for (int mi = 0; mi < 4; ++mi) {
    const int gmb = m0 + wm + mi * 16 + quad * 4;
#pragma unroll
    for (int ni = 0; ni < 4; ++ni) {
      const int n = n0 + wn + ni * 16 + l16;
      const float bv = bias[n];
#pragma unroll
      for (int r = 0; r < 4; ++r)
        Cout[(long)(gmb + r) * N + n] = acc[mi][ni][r] + bv;
    }
  }
}

extern "C" void kernel_launch(void* const* d_in, const int* in_sizes, int n_in,
                              void* d_out, int out_size, void* d_ws, size_t ws_size,
                              hipStream_t stream) {
  const float* x  = (const float*)d_in[0];
  const float* wq = (const float*)d_in[1];
  const float* wk = (const float*)d_in[2];
  const float* wv = (const float*)d_in[3];
  const float* wo = (const float*)d_in[4];
  const float* bo = (const float*)d_in[5];
  float* out = (float*)d_out;

  // workspace: Q,K,V [b,h,t,64] + ctx [b,t,D], bf16 (32 MB)
  bf16* Qb = (bf16*)d_ws;
  bf16* Kb = Qb + 4194304;
  bf16* Vb = Kb + 4194304;
  bf16* Cx = Vb + 4194304;

  hipLaunchKernelGGL(gemm_qkv, dim3(24, 32), dim3(256), 0, stream,
                     x, wq, wk, wv, Qb, Kb, Vb, 4096, 1024);

  hipLaunchKernelGGL(attn_kernel, dim3(32, 32), dim3(256), 0, stream, Qb, Kb, Vb, Cx);

  hipLaunchKernelGGL(gemm_out, dim3(8, 32), dim3(256), 0, stream,
                     Cx, wo, bo, out, 4096, 1024, 1024);
}

// Round 8
// 274.956 us; speedup vs baseline: 16.5571x; 1.3046x over previous
//
#include <hip/hip_runtime.h>
#include <hip/hip_bf16.h>
#include <cstdint>

typedef __hip_bfloat16 bf16;
typedef __bf16 bf16x8 __attribute__((ext_vector_type(8)));
typedef __bf16 bf16x4 __attribute__((ext_vector_type(4)));
typedef float f32x4 __attribute__((ext_vector_type(4)));

#define LOG2E 1.4426950408889634f

// ---- QKV GEMM: C = x[M,K](f32) * W[K,1024](f32->bf16), 128x128 tile, BK=32 ----
// Register-prefetch pipeline: next tile's global loads issue during MFMA.
__global__ __launch_bounds__(256, 2) void gemm_qkv(
    const float* __restrict__ A,
    const float* __restrict__ Wq, const float* __restrict__ Wk, const float* __restrict__ Wv,
    bf16* __restrict__ Cq, bf16* __restrict__ Ck, bf16* __restrict__ Cv,
    int M, int K) {
  constexpr int BM = 128, BK = 32, BSTR = 40;
  __shared__ __align__(16) bf16 As[BM * BK];
  __shared__ __align__(16) bf16 Bs[128 * BSTR];

  const int tid = threadIdx.x;
  const int lane = tid & 63;
  const int wave = tid >> 6;
  const int quad = lane >> 4;
  const int l16 = lane & 15;
  const int m0 = blockIdx.y * BM;
  const int n0 = blockIdx.x * 128;
  const int wm = (wave >> 1) * 64;
  const int wn = (wave & 1) * 64;

  const float* W = (n0 < 1024) ? Wq : ((n0 < 2048) ? Wk : Wv);
  const int nloc = n0 & 1023;

  const f32x4 zero4 = {0.f, 0.f, 0.f, 0.f};
  f32x4 acc[4][4];
#pragma unroll
  for (int mi = 0; mi < 4; ++mi)
#pragma unroll
    for (int ni = 0; ni < 4; ++ni) acc[mi][ni] = zero4;

  const int arow = tid >> 1;
  const int ac = (tid & 1) * 16;
  const float* agp = A + (long)(m0 + arow) * K + ac;
  const int bkq = (tid >> 5) * 4;
  const int bn4 = (tid & 31) * 4;
  const float* wgp = W + (long)bkq * 1024 + nloc + bn4;

  f32x4 apre[4], wpre[4];
  {
    const f32x4* ap = (const f32x4*)agp;
#pragma unroll
    for (int i = 0; i < 4; ++i) apre[i] = ap[i];
#pragma unroll
    for (int i = 0; i < 4; ++i) wpre[i] = *(const f32x4*)(wgp + i * 1024);
  }

  const int NK = K / BK;
  for (int kt = 0; kt < NK; ++kt) {
    // convert + store prefetched tile
    {
      bf16x8 v0, v1;
#pragma unroll
      for (int j = 0; j < 4; ++j) { v0[j] = (__bf16)apre[0][j]; v0[4 + j] = (__bf16)apre[1][j]; }
#pragma unroll
      for (int j = 0; j < 4; ++j) { v1[j] = (__bf16)apre[2][j]; v1[4 + j] = (__bf16)apre[3][j]; }
      *(bf16x8*)&As[arow * BK + ac] = v0;
      *(bf16x8*)&As[arow * BK + ac + 8] = v1;
#pragma unroll
      for (int j = 0; j < 4; ++j) {
        bf16x4 t;
        t[0] = (__bf16)wpre[0][j]; t[1] = (__bf16)wpre[1][j];
        t[2] = (__bf16)wpre[2][j]; t[3] = (__bf16)wpre[3][j];
        *(bf16x4*)&Bs[(bn4 + j) * BSTR + bkq] = t;
      }
    }
    __syncthreads();
    if (kt + 1 < NK) {
      const int k0 = (kt + 1) * BK;
      const f32x4* ap = (const f32x4*)(agp + k0);
#pragma unroll
      for (int i = 0; i < 4; ++i) apre[i] = ap[i];
#pragma unroll
      for (int i = 0; i < 4; ++i) wpre[i] = *(const f32x4*)(wgp + (long)k0 * 1024 + i * 1024);
    }

    bf16x8 af[4], bfv[4];
#pragma unroll
    for (int mi = 0; mi < 4; ++mi)
      af[mi] = *(const bf16x8*)&As[(wm + mi * 16 + l16) * BK + quad * 8];
#pragma unroll
    for (int ni = 0; ni < 4; ++ni)
      bfv[ni] = *(const bf16x8*)&Bs[(wn + ni * 16 + l16) * BSTR + quad * 8];
#pragma unroll
    for (int mi = 0; mi < 4; ++mi)
#pragma unroll
      for (int ni = 0; ni < 4; ++ni)
        acc[mi][ni] = __builtin_amdgcn_mfma_f32_16x16x32_bf16(af[mi], bfv[ni], acc[mi][ni], 0, 0, 0);
    __syncthreads();
  }

#pragma unroll
  for (int mi = 0; mi < 4; ++mi) {
    const int gmb = m0 + wm + mi * 16 + quad * 4;
#pragma unroll
    for (int ni = 0; ni < 4; ++ni) {
      const int n = n0 + wn + ni * 16 + l16;
      const int which = n >> 10, rem = n & 1023;
      const int h = rem >> 6, hd = rem & 63;
      bf16* dst = (which == 0) ? Cq : ((which == 1) ? Ck : Cv);
#pragma unroll
      for (int r = 0; r < 4; ++r) {
        const int gm = gmb + r;
        const int b = gm >> 11, t = gm & 2047;
        dst[(((long)(b * 16 + h)) * 2048 + t) * 64 + hd] = __float2bfloat16(acc[mi][ni][r]);
      }
    }
  }
}

// ---- flash attention v2: Q-tile 64, K-tile 128, reg prefetch, LPT ordering ----
// grid (32, 32): qt = 31 - blockIdx.x (longest blocks first); block 256 (4 waves)
__global__ __launch_bounds__(256, 3) void attn_kernel(
    const bf16* __restrict__ Q, const bf16* __restrict__ Kg, const bf16* __restrict__ Vg,
    bf16* __restrict__ ctx) {
  constexpr int KSTR = 72, VSTR = 136, PSTR = 136;
  __shared__ __align__(16) bf16 Ks[128 * KSTR];      // [t_local 0..127][d 0..63]
  __shared__ __align__(16) bf16 Vt[64 * VSTR];       // [d][t_local 0..127]
  __shared__ __align__(16) bf16 Ps[4 * 16 * PSTR];   // per-wave P [16][128]

  const int tid = threadIdx.x;
  const int lane = tid & 63;
  const int wave = tid >> 6;
  const int quad = lane >> 4;
  const int l16 = lane & 15;
  const int qt = (int)gridDim.x - 1 - (int)blockIdx.x;  // LPT: big qt first
  const int bh = blockIdx.y;
  const long base = (long)bh * 2048 * 64;
  const int qrow = qt * 64 + wave * 16;

  const bf16x8 qf0 = *(const bf16x8*)(Q + base + (long)(qrow + l16) * 64 + quad * 8);
  const bf16x8 qf1 = *(const bf16x8*)(Q + base + (long)(qrow + l16) * 64 + 32 + quad * 8);

  const f32x4 zero4 = {0.f, 0.f, 0.f, 0.f};
  float m_i[4], l_i[4];
  f32x4 oacc[4];
#pragma unroll
  for (int r = 0; r < 4; ++r) { m_i[r] = -1e30f; l_i[r] = 0.f; }
#pragma unroll
  for (int nb = 0; nb < 4; ++nb) oacc[nb] = zero4;

  // staging map: 128 rows x 64 d / 256 threads = 32 elems (4x bf16x8) each
  const int srow = tid >> 1;          // 0..127 (t within tile)
  const int scol = (tid & 1) * 32;    // 0 or 32 (d)

  const int nk = (qt + 2) >> 1;       // #128-wide K tiles
  bf16x8 kr[4], vr[4];
  {
    const bf16* kp = Kg + base + (long)srow * 64 + scol;
    const bf16* vp = Vg + base + (long)srow * 64 + scol;
#pragma unroll
    for (int i = 0; i < 4; ++i) kr[i] = *(const bf16x8*)(kp + i * 8);
#pragma unroll
    for (int i = 0; i < 4; ++i) vr[i] = *(const bf16x8*)(vp + i * 8);
  }

  for (int kt = 0; kt < nk; ++kt) {
    const int k0 = kt * 128;
    // store staged K/V
#pragma unroll
    for (int i = 0; i < 4; ++i)
      *(bf16x8*)&Ks[srow * KSTR + scol + i * 8] = kr[i];
#pragma unroll
    for (int i = 0; i < 4; ++i) {
      const bf16* vh = (const bf16*)&vr[i];
#pragma unroll
      for (int j = 0; j < 8; ++j)
        Vt[(scol + i * 8 + j) * VSTR + srow] = vh[j];
    }
    __syncthreads();
    if (kt + 1 < nk) {
      const bf16* kp = Kg + base + (long)(k0 + 128 + srow) * 64 + scol;
      const bf16* vp = Vg + base + (long)(k0 + 128 + srow) * 64 + scol;
#pragma unroll
      for (int i = 0; i < 4; ++i) kr[i] = *(const bf16x8*)(kp + i * 8);
#pragma unroll
      for (int i = 0; i < 4; ++i) vr[i] = *(const bf16x8*)(vp + i * 8);
    }

    // S = Q K^T  (16 q-rows x 128 k-cols per wave)
    f32x4 s[8];
#pragma unroll
    for (int nb = 0; nb < 8; ++nb) {
      const bf16x8 kb0 = *(const bf16x8*)&Ks[(nb * 16 + l16) * KSTR + quad * 8];
      const bf16x8 kb1 = *(const bf16x8*)&Ks[(nb * 16 + l16) * KSTR + 32 + quad * 8];
      f32x4 a = zero4;
      a = __builtin_amdgcn_mfma_f32_16x16x32_bf16(qf0, kb0, a, 0, 0, 0);
      a = __builtin_amdgcn_mfma_f32_16x16x32_bf16(qf1, kb1, a, 0, 0, 0);
      s[nb] = a;
    }

    // scale + causal mask + row max
    float mp[4];
#pragma unroll
    for (int r = 0; r < 4; ++r) mp[r] = -1e30f;
#pragma unroll
    for (int nb = 0; nb < 8; ++nb) {
      const int kidx = k0 + nb * 16 + l16;
#pragma unroll
      for (int r = 0; r < 4; ++r) {
        const int qidx = qrow + quad * 4 + r;
        float sv = s[nb][r] * 0.125f;
        sv = (kidx <= qidx) ? sv : -1e30f;
        s[nb][r] = sv;
        mp[r] = fmaxf(mp[r], sv);
      }
    }
#pragma unroll
    for (int r = 0; r < 4; ++r) {
      float v = mp[r];
      v = fmaxf(v, __shfl_xor(v, 1));
      v = fmaxf(v, __shfl_xor(v, 2));
      v = fmaxf(v, __shfl_xor(v, 4));
      v = fmaxf(v, __shfl_xor(v, 8));
      mp[r] = v;
    }

    float alpha[4], mn[4], rs[4];
#pragma unroll
    for (int r = 0; r < 4; ++r) {
      mn[r] = fmaxf(m_i[r], mp[r]);
      alpha[r] = exp2f((m_i[r] - mn[r]) * LOG2E);
      rs[r] = 0.f;
    }
#pragma unroll
    for (int nb = 0; nb < 8; ++nb)
#pragma unroll
      for (int r = 0; r < 4; ++r) {
        const float p = exp2f((s[nb][r] - mn[r]) * LOG2E);
        rs[r] += p;
        Ps[wave * (16 * PSTR) + (quad * 4 + r) * PSTR + nb * 16 + l16] = __float2bfloat16(p);
      }
#pragma unroll
    for (int r = 0; r < 4; ++r) {
      float v = rs[r];
      v += __shfl_xor(v, 1);
      v += __shfl_xor(v, 2);
      v += __shfl_xor(v, 4);
      v += __shfl_xor(v, 8);
      l_i[r] = l_i[r] * alpha[r] + v;
      m_i[r] = mn[r];
    }
#pragma unroll
    for (int nb = 0; nb < 4; ++nb)
#pragma unroll
      for (int r = 0; r < 4; ++r) oacc[nb][r] *= alpha[r];

    __asm__ volatile("s_waitcnt lgkmcnt(0)" ::: "memory");

    // O += P V  over 128-wide k (4 kk chunks of 32)
    bf16x8 pa[4];
#pragma unroll
    for (int kk = 0; kk < 4; ++kk)
      pa[kk] = *(const bf16x8*)&Ps[wave * (16 * PSTR) + l16 * PSTR + kk * 32 + quad * 8];
#pragma unroll
    for (int nb2 = 0; nb2 < 4; ++nb2) {
#pragma unroll
      for (int kk = 0; kk < 4; ++kk) {
        const bf16x8 vb = *(const bf16x8*)&Vt[(nb2 * 16 + l16) * VSTR + kk * 32 + quad * 8];
        oacc[nb2] = __builtin_amdgcn_mfma_f32_16x16x32_bf16(pa[kk], vb, oacc[nb2], 0, 0, 0);
      }
    }
    __syncthreads();
  }

  // epilogue: ctx[b, t, h*64+hd] bf16
  const int b = bh >> 4, h = bh & 15;
#pragma unroll
  for (int r = 0; r < 4; ++r) {
    const float inv = 1.0f / l_i[r];
    const int t = qrow + quad * 4 + r;
#pragma unroll
    for (int nb2 = 0; nb2 < 4; ++nb2) {
      const int d = h * 64 + nb2 * 16 + l16;
      ctx[((long)b * 2048 + t) * 1024 + d] = __float2bfloat16(oacc[nb2][r] * inv);
    }
  }
}

// ---- output GEMM: ctx[M,K](bf16) @ wo[K,N](f32) + bo(f32) -> out f32 ----
__global__ __launch_bounds__(256, 2) void gemm_out(
    const bf16* __restrict__ A, const float* __restrict__ W,
    const float* __restrict__ bias, float* __restrict__ Cout,
    int M, int N, int K) {
  constexpr int BM = 128, BK = 32, BSTR = 40;
  __shared__ __align__(16) bf16 As[BM * BK];
  __shared__ __align__(16) bf16 Bs[128 * BSTR];

  const int tid = threadIdx.x;
  const int lane = tid & 63;
  const int wave = tid >> 6;
  const int quad = lane >> 4;
  const int l16 = lane & 15;
  const int m0 = blockIdx.y * BM;
  const int n0 = blockIdx.x * 128;
  const int wm = (wave >> 1) * 64;
  const int wn = (wave & 1) * 64;

  const f32x4 zero4 = {0.f, 0.f, 0.f, 0.f};
  f32x4 acc[4][4];
#pragma unroll
  for (int mi = 0; mi < 4; ++mi)
#pragma unroll
    for (int ni = 0; ni < 4; ++ni) acc[mi][ni] = zero4;

  const int arow = tid >> 1;
  const int ac = (tid & 1) * 16;
  const bf16* agp = A + (long)(m0 + arow) * K + ac;
  const int bkq = (tid >> 5) * 4;
  const int bn4 = (tid & 31) * 4;
  const float* wgp = W + (long)bkq * 1024 + n0 + bn4;

  bf16x8 apre[2];
  f32x4 wpre[4];
  {
    apre[0] = *(const bf16x8*)agp;
    apre[1] = *(const bf16x8*)(agp + 8);
#pragma unroll
    for (int i = 0; i < 4; ++i) wpre[i] = *(const f32x4*)(wgp + i * 1024);
  }

  const int NK = K / BK;
  for (int kt = 0; kt < NK; ++kt) {
    {
      *(bf16x8*)&As[arow * BK + ac] = apre[0];
      *(bf16x8*)&As[arow * BK + ac + 8] = apre[1];
#pragma unroll
      for (int j = 0; j < 4; ++j) {
        bf16x4 t;
        t[0] = (__bf16)wpre[0][j]; t[1] = (__bf16)wpre[1][j];
        t[2] = (__bf16)wpre[2][j]; t[3] = (__bf16)wpre[3][j];
        *(bf16x4*)&Bs[(bn4 + j) * BSTR + bkq] = t;
      }
    }
    __syncthreads();
    if (kt + 1 < NK) {
      const int k0 = (kt + 1) * BK;
      apre[0] = *(const bf16x8*)(agp + k0);
      apre[1] = *(const bf16x8*)(agp + k0 + 8);
#pragma unroll
      for (int i = 0; i < 4; ++i) wpre[i] = *(const f32x4*)(wgp + (long)k0 * 1024 + i * 1024);
    }

    bf16x8 af[4], bfv[4];
#pragma unroll
    for (int mi = 0; mi < 4; ++mi)
      af[mi] = *(const bf16x8*)&As[(wm + mi * 16 + l16) * BK + quad * 8];
#pragma unroll
    for (int ni = 0; ni < 4; ++ni)
      bfv[ni] = *(const bf16x8*)&Bs[(wn + ni * 16 + l16) * BSTR + quad * 8];
#pragma unroll
    for (int mi = 0; mi < 4; ++mi)
#pragma unroll
      for (int ni = 0; ni < 4; ++ni)
        acc[mi][ni] = __builtin_amdgcn_mfma_f32_16x16x32_bf16(af[mi], bfv[ni], acc[mi][ni], 0, 0, 0);
    __syncthreads();
  }

#pragma unroll
  for (int mi = 0; mi < 4; ++mi) {
    const int gmb = m0 + wm + mi * 16 + quad * 4;
#pragma unroll
    for (int ni = 0; ni < 4; ++ni) {
      const int n = n0 + wn + ni * 16 + l16;
      const float bv = bias[n];
#pragma unroll
      for (int r = 0; r < 4; ++r)
        Cout[(long)(gmb + r) * N + n] = acc[mi][ni][r] + bv;
    }
  }
}

extern "C" void kernel_launch(void* const* d_in, const int* in_sizes, int n_in,
                              void* d_out, int out_size, void* d_ws, size_t ws_size,
                              hipStream_t stream) {
  const float* x  = (const float*)d_in[0];
  const float* wq = (const float*)d_in[1];
  const float* wk = (const float*)d_in[2];
  const float* wv = (const float*)d_in[3];
  const float* wo = (const float*)d_in[4];
  const float* bo = (const float*)d_in[5];
  float* out = (float*)d_out;

  bf16* Qb = (bf16*)d_ws;
  bf16* Kb = Qb + 4194304;
  bf16* Vb = Kb + 4194304;
  bf16* Cx = Vb + 4194304;

  hipLaunchKernelGGL(gemm_qkv, dim3(24, 32), dim3(256), 0, stream,
                     x, wq, wk, wv, Qb, Kb, Vb, 4096, 1024);

  hipLaunchKernelGGL(attn_kernel, dim3(32, 32), dim3(256), 0, stream, Qb, Kb, Vb, Cx);

  hipLaunchKernelGGL(gemm_out, dim3(8, 32), dim3(256), 0, stream,
                     Cx, wo, bo, out, 4096, 1024, 1024);
}

// Round 9
// 242.145 us; speedup vs baseline: 18.8007x; 1.1355x over previous
//
#include <hip/hip_runtime.h>
#include <hip/hip_bf16.h>
#include <cstdint>

typedef __hip_bfloat16 bf16;
typedef __bf16 bf16x8 __attribute__((ext_vector_type(8)));
typedef __bf16 bf16x4 __attribute__((ext_vector_type(4)));
typedef float f32x4 __attribute__((ext_vector_type(4)));

#define LOG2E 1.4426950408889634f

__device__ __forceinline__ void gload_lds16(const void* g, void* l) {
  __builtin_amdgcn_global_load_lds(
      (const __attribute__((address_space(1))) unsigned int*)g,
      (__attribute__((address_space(3))) unsigned int*)l,
      16, 0, 0);
}

// ---- f32 -> bf16 flat convert, 8 elems/thread ----
__global__ void conv_k(const float* __restrict__ src, bf16* __restrict__ dst, int n) {
  const int i = (blockIdx.x * 256 + threadIdx.x) * 8;
  if (i >= n) return;
  const f32x4 a = *(const f32x4*)(src + i);
  const f32x4 b = *(const f32x4*)(src + i + 4);
  bf16x8 o;
#pragma unroll
  for (int j = 0; j < 4; ++j) { o[j] = (__bf16)a[j]; o[4 + j] = (__bf16)b[j]; }
  *(bf16x8*)(dst + i) = o;
}

// ---- 32x32 LDS-tiled transpose + f32->bf16: dst[c][r] = bf16(src[r][c]) ----
__global__ void transpose_conv_k(const float* __restrict__ src, bf16* __restrict__ dst, int n) {
  __shared__ float tile[32][33];
  const int bx = blockIdx.x * 32, by = blockIdx.y * 32;
  const int tx = threadIdx.x;
  for (int j = threadIdx.y; j < 32; j += 8)
    tile[j][tx] = src[(long)(by + j) * n + bx + tx];
  __syncthreads();
  for (int j = threadIdx.y; j < 32; j += 8)
    dst[(long)(bx + j) * n + by + tx] = __float2bfloat16(tile[tx][j]);
}

// ---- m97-style GEMM: C = A[M,K](bf16) * Bt[N,K](bf16)^T, 128x128, BK=32,
//      global_load_lds width=16 staging.
// MODE 0: scatter -> Q,K,V [b,h,t,64] bf16.  MODE 1: f32 out + f32 bias.
template <int MODE>
__global__ __launch_bounds__(256, 2) void gemm_bt(
    const bf16* __restrict__ A, const bf16* __restrict__ Bt,
    bf16* __restrict__ Cq, bf16* __restrict__ Ck, bf16* __restrict__ Cv,
    const float* __restrict__ bias, float* __restrict__ Cout,
    int M, int N, int K) {
  __shared__ __align__(16) bf16 As[128 * 32];
  __shared__ __align__(16) bf16 Bs[128 * 32];

  const int tid = threadIdx.x;
  const int lane = tid & 63;
  const int wave = tid >> 6;
  const int quad = lane >> 4;
  const int l16 = lane & 15;
  const int m0 = blockIdx.y * 128;
  const int n0 = blockIdx.x * 128;
  const int wm = (wave >> 1) * 64;
  const int wn = (wave & 1) * 64;

  const f32x4 zero4 = {0.f, 0.f, 0.f, 0.f};
  f32x4 acc[4][4];
#pragma unroll
  for (int mi = 0; mi < 4; ++mi)
#pragma unroll
    for (int ni = 0; ni < 4; ++ni) acc[mi][ni] = zero4;

  // staging: flat = tid*8 ; row = flat/32, k = flat%32 (matches lane-ordered LDS dest)
  const int sRow = tid >> 2;
  const int sK = (tid & 3) * 8;
  const bf16* Ag = A + (long)(m0 + sRow) * K + sK;
  const bf16* Ag2 = Ag + 64L * K;
  const bf16* Bg = Bt + (long)(n0 + sRow) * K + sK;
  const bf16* Bg2 = Bg + 64L * K;

  for (int k0 = 0; k0 < K; k0 += 32) {
    gload_lds16(Ag + k0, &As[tid * 8]);
    gload_lds16(Ag2 + k0, &As[tid * 8 + 2048]);
    gload_lds16(Bg + k0, &Bs[tid * 8]);
    gload_lds16(Bg2 + k0, &Bs[tid * 8 + 2048]);
    __syncthreads();

    bf16x8 af[4], bfv[4];
#pragma unroll
    for (int mi = 0; mi < 4; ++mi)
      af[mi] = *(const bf16x8*)&As[(wm + mi * 16 + l16) * 32 + quad * 8];
#pragma unroll
    for (int ni = 0; ni < 4; ++ni)
      bfv[ni] = *(const bf16x8*)&Bs[(wn + ni * 16 + l16) * 32 + quad * 8];
#pragma unroll
    for (int mi = 0; mi < 4; ++mi)
#pragma unroll
      for (int ni = 0; ni < 4; ++ni)
        acc[mi][ni] = __builtin_amdgcn_mfma_f32_16x16x32_bf16(af[mi], bfv[ni], acc[mi][ni], 0, 0, 0);
    __syncthreads();
  }

#pragma unroll
  for (int mi = 0; mi < 4; ++mi) {
    const int gmb = m0 + wm + mi * 16 + quad * 4;
#pragma unroll
    for (int ni = 0; ni < 4; ++ni) {
      const int n = n0 + wn + ni * 16 + l16;
      if (MODE == 0) {
        const int which = n >> 10, rem = n & 1023;
        const int h = rem >> 6, hd = rem & 63;
        bf16* dst = (which == 0) ? Cq : ((which == 1) ? Ck : Cv);
#pragma unroll
        for (int r = 0; r < 4; ++r) {
          const int gm = gmb + r;
          const int b = gm >> 11, t = gm & 2047;
          dst[(((long)(b * 16 + h)) * 2048 + t) * 64 + hd] = __float2bfloat16(acc[mi][ni][r]);
        }
      } else {
        const float bv = bias[n];
#pragma unroll
        for (int r = 0; r < 4; ++r)
          Cout[(long)(gmb + r) * N + n] = acc[mi][ni][r] + bv;
      }
    }
  }
}

// ---- flash attention v3: S^T trick (per-lane softmax state), packed LDS ----
// grid (32, 32): qt = 31 - blockIdx.x (LPT); block 256 (4 waves, 16 q-rows each)
__global__ __launch_bounds__(256, 3) void attn_kernel(
    const bf16* __restrict__ Q, const bf16* __restrict__ Kg, const bf16* __restrict__ Vg,
    bf16* __restrict__ ctx) {
  constexpr int KSTR = 72, VSTR = 136, PSTR = 136;
  __shared__ __align__(16) bf16 Ks[128 * KSTR];     // [t][d]
  __shared__ __align__(16) bf16 Vt[64 * VSTR];      // [d][t]
  __shared__ __align__(16) bf16 Ps[4 * 16 * PSTR];  // per-wave [q][k]

  const int tid = threadIdx.x;
  const int lane = tid & 63;
  const int wave = tid >> 6;
  const int quad = lane >> 4;
  const int l16 = lane & 15;
  const int qt = (int)gridDim.x - 1 - (int)blockIdx.x;
  const int bh = blockIdx.y;
  const long base = (long)bh * 2048 * 64;
  const int qbase = qt * 64 + wave * 16;
  const int q = qbase + l16;  // this lane's softmax row

  const bf16x8 qf0 = *(const bf16x8*)(Q + base + (long)(qbase + l16) * 64 + quad * 8);
  const bf16x8 qf1 = *(const bf16x8*)(Q + base + (long)(qbase + l16) * 64 + 32 + quad * 8);

  const f32x4 zero4 = {0.f, 0.f, 0.f, 0.f};
  float m_i = -1e30f, l_i = 0.f;
  f32x4 oacc[4];
#pragma unroll
  for (int nb = 0; nb < 4; ++nb) oacc[nb] = zero4;

  // K staging: 2 threads per row, 32-d halves
  const int krow = tid >> 1;
  const int kc32 = (tid & 1) * 32;
  // V staging: 4 t-rows x 8 d per thread (register transpose -> b64 writes)
  const int vr4 = (tid & 31) * 4;
  const int vd8 = (tid >> 5) * 8;

  const int nk = (qt + 2) >> 1;
  bf16x8 kr[4], vv[4];
  {
    const bf16* kp = Kg + base + (long)krow * 64 + kc32;
#pragma unroll
    for (int i = 0; i < 4; ++i) kr[i] = *(const bf16x8*)(kp + i * 8);
#pragma unroll
    for (int i = 0; i < 4; ++i)
      vv[i] = *(const bf16x8*)(Vg + base + (long)(vr4 + i) * 64 + vd8);
  }

  for (int kt = 0; kt < nk; ++kt) {
    const int k0 = kt * 128;
#pragma unroll
    for (int i = 0; i < 4; ++i)
      *(bf16x8*)&Ks[krow * KSTR + kc32 + i * 8] = kr[i];
#pragma unroll
    for (int j = 0; j < 8; ++j) {
      bf16x4 t;
      t[0] = vv[0][j]; t[1] = vv[1][j]; t[2] = vv[2][j]; t[3] = vv[3][j];
      *(bf16x4*)&Vt[(vd8 + j) * VSTR + vr4] = t;
    }
    __syncthreads();
    if (kt + 1 < nk) {
      const bf16* kp = Kg + base + (long)(k0 + 128 + krow) * 64 + kc32;
#pragma unroll
      for (int i = 0; i < 4; ++i) kr[i] = *(const bf16x8*)(kp + i * 8);
#pragma unroll
      for (int i = 0; i < 4; ++i)
        vv[i] = *(const bf16x8*)(Vg + base + (long)(k0 + 128 + vr4 + i) * 64 + vd8);
    }

    // S^T = mfma(K-frag, Q-frag): lane holds S^T[k=k0+kb*16+quad*4+r][q=l16]
    f32x4 s[8];
#pragma unroll
    for (int kb = 0; kb < 8; ++kb) {
      const bf16x8 kb0 = *(const bf16x8*)&Ks[(kb * 16 + l16) * KSTR + quad * 8];
      const bf16x8 kb1 = *(const bf16x8*)&Ks[(kb * 16 + l16) * KSTR + 32 + quad * 8];
      f32x4 a = zero4;
      a = __builtin_amdgcn_mfma_f32_16x16x32_bf16(kb0, qf0, a, 0, 0, 0);
      a = __builtin_amdgcn_mfma_f32_16x16x32_bf16(kb1, qf1, a, 0, 0, 0);
      s[kb] = a;
    }

    // scale + causal + per-lane max over 32 elems, then cross-quad reduce
    float mloc = -1e30f;
#pragma unroll
    for (int kb = 0; kb < 8; ++kb) {
#pragma unroll
      for (int r = 0; r < 4; ++r) {
        const int kidx = k0 + kb * 16 + quad * 4 + r;
        float sv = s[kb][r] * 0.125f;
        sv = (kidx <= q) ? sv : -1e30f;
        s[kb][r] = sv;
        mloc = fmaxf(mloc, sv);
      }
    }
    mloc = fmaxf(mloc, __shfl_xor(mloc, 16));
    mloc = fmaxf(mloc, __shfl_xor(mloc, 32));

    const float mn = fmaxf(m_i, mloc);
    const float alpha = exp2f((m_i - mn) * LOG2E);
    float rsum = 0.f;
#pragma unroll
    for (int kb = 0; kb < 8; ++kb) {
      bf16x4 pk;
#pragma unroll
      for (int r = 0; r < 4; ++r) {
        const float p = exp2f((s[kb][r] - mn) * LOG2E);
        rsum += p;
        pk[r] = (__bf16)p;
      }
      *(bf16x4*)&Ps[wave * (16 * PSTR) + l16 * PSTR + kb * 16 + quad * 4] = pk;
    }
    rsum += __shfl_xor(rsum, 16);
    rsum += __shfl_xor(rsum, 32);
    l_i = l_i * alpha + rsum;
    m_i = mn;

    // broadcast alpha to O C-layout rows (q = quad*4+r)
    float alr[4];
#pragma unroll
    for (int r = 0; r < 4; ++r) alr[r] = __shfl(alpha, quad * 4 + r);
#pragma unroll
    for (int nb = 0; nb < 4; ++nb)
#pragma unroll
      for (int r = 0; r < 4; ++r) oacc[nb][r] *= alr[r];

    __asm__ volatile("s_waitcnt lgkmcnt(0)" ::: "memory");

    // O += P V
    bf16x8 pa[4];
#pragma unroll
    for (int kk = 0; kk < 4; ++kk)
      pa[kk] = *(const bf16x8*)&Ps[wave * (16 * PSTR) + l16 * PSTR + kk * 32 + quad * 8];
#pragma unroll
    for (int nb2 = 0; nb2 < 4; ++nb2) {
#pragma unroll
      for (int kk = 0; kk < 4; ++kk) {
        const bf16x8 vb = *(const bf16x8*)&Vt[(nb2 * 16 + l16) * VSTR + kk * 32 + quad * 8];
        oacc[nb2] = __builtin_amdgcn_mfma_f32_16x16x32_bf16(pa[kk], vb, oacc[nb2], 0, 0, 0);
      }
    }
    __syncthreads();
  }

  // epilogue
  const int b = bh >> 4, h = bh & 15;
  float linv[4];
#pragma unroll
  for (int r = 0; r < 4; ++r) linv[r] = 1.0f / __shfl(l_i, quad * 4 + r);
#pragma unroll
  for (int r = 0; r < 4; ++r) {
    const int t = qbase + quad * 4 + r;
#pragma unroll
    for (int nb2 = 0; nb2 < 4; ++nb2) {
      const int d = h * 64 + nb2 * 16 + l16;
      ctx[((long)b * 2048 + t) * 1024 + d] = __float2bfloat16(oacc[nb2][r] * linv[r]);
    }
  }
}

extern "C" void kernel_launch(void* const* d_in, const int* in_sizes, int n_in,
                              void* d_out, int out_size, void* d_ws, size_t ws_size,
                              hipStream_t stream) {
  const float* x  = (const float*)d_in[0];
  const float* wq = (const float*)d_in[1];
  const float* wk = (const float*)d_in[2];
  const float* wv = (const float*)d_in[3];
  const float* wo = (const float*)d_in[4];
  const float* bo = (const float*)d_in[5];
  float* out = (float*)d_out;

  // ws (bf16 elems), ~42 MB total; Cx aliases xb (dead after gemm_qkv)
  bf16* Wtqkv = (bf16*)d_ws;            // 3 * 1048576
  bf16* Wto   = Wtqkv + 3145728;        // 1048576
  bf16* xb    = Wto + 1048576;          // 4194304 (later reused as Cx)
  bf16* Qb    = xb + 4194304;
  bf16* Kb    = Qb + 4194304;
  bf16* Vb    = Kb + 4194304;
  bf16* Cx    = xb;

  hipLaunchKernelGGL(conv_k, dim3(2048), dim3(256), 0, stream, x, xb, 4194304);
  dim3 tb(32, 8), tg(32, 32);
  hipLaunchKernelGGL(transpose_conv_k, tg, tb, 0, stream, wq, Wtqkv, 1024);
  hipLaunchKernelGGL(transpose_conv_k, tg, tb, 0, stream, wk, Wtqkv + 1048576, 1024);
  hipLaunchKernelGGL(transpose_conv_k, tg, tb, 0, stream, wv, Wtqkv + 2097152, 1024);
  hipLaunchKernelGGL(transpose_conv_k, tg, tb, 0, stream, wo, Wto, 1024);

  hipLaunchKernelGGL((gemm_bt<0>), dim3(24, 32), dim3(256), 0, stream,
                     xb, Wtqkv, Qb, Kb, Vb, (const float*)nullptr, (float*)nullptr,
                     4096, 3072, 1024);

  hipLaunchKernelGGL(attn_kernel, dim3(32, 32), dim3(256), 0, stream, Qb, Kb, Vb, Cx);

  hipLaunchKernelGGL((gemm_bt<1>), dim3(8, 32), dim3(256), 0, stream,
                     Cx, Wto, (bf16*)nullptr, (bf16*)nullptr, (bf16*)nullptr, bo, out,
                     4096, 1024, 1024);
}